// Round 3
// baseline (989.957 us; speedup 1.0000x reference)
//
#include <hip/hip_runtime.h>

#define B_ 8
#define T_ 1024
#define C_ 1024
#define E_ 8
#define H_ 4096

typedef float v4f __attribute__((ext_vector_type(4)));
typedef short v8s __attribute__((ext_vector_type(8)));

__device__ __forceinline__ unsigned short f2bf(float f) {
  union { float f; unsigned int u; } x; x.f = f;
  unsigned int r = x.u + 0x7fffu + ((x.u >> 16) & 1u);
  return (unsigned short)(r >> 16);
}

__device__ __forceinline__ void async_load16(const unsigned short* g, unsigned short* l) {
  __builtin_amdgcn_global_load_lds(
      (const __attribute__((address_space(1))) void*)g,
      (__attribute__((address_space(3))) void*)l, 16, 0, 0);
}

// ---------------- router phase ----------------

// stage 1: partial sums over T in 32 chunks of 32; also emits bf16 cast of x.
// part[tc][b][c], tc in [0,32)
__global__ void k_meanpart(const float* __restrict__ x, float* __restrict__ part,
                           unsigned short* __restrict__ xb) {
  int b = blockIdx.x >> 5, tc = blockIdx.x & 31;
  int c4 = threadIdx.x * 4;
  const size_t base = (size_t)b * T_ * C_ + (size_t)tc * 32 * C_ + c4;
  const float* xp = x + base;
  v4f s = {0.f, 0.f, 0.f, 0.f};
  for (int t = 0; t < 32; ++t) {
    v4f v = *(const v4f*)(xp + (size_t)t * C_);
    s += v;
    ushort4 o;
    o.x = f2bf(v.x); o.y = f2bf(v.y); o.z = f2bf(v.z); o.w = f2bf(v.w);
    *(ushort4*)(xb + base + (size_t)t * C_) = o;
  }
  *(v4f*)(part + (size_t)(tc * B_ + b) * C_ + c4) = s;
}

// stage 2: single block: seq_rep, logits, softmax, top-2, weights, loss
__global__ void k_router(const float* __restrict__ part, const float* __restrict__ rw,
                         int* __restrict__ sel, float* __restrict__ wv,
                         float* __restrict__ loss_out) {
  __shared__ float seq[B_ * C_];
  __shared__ float red[B_ * E_][4];
  __shared__ float pr[B_][E_];
  __shared__ int ss[B_][2];
  const int tid = threadIdx.x;
  for (int idx = tid; idx < B_ * C_; idx += 256) {
    float s = 0.f;
#pragma unroll
    for (int tc = 0; tc < 32; ++tc) s += part[(size_t)tc * B_ * C_ + idx];
    seq[idx] = s * (1.0f / T_);
  }
  __syncthreads();
  {
    int pair = tid >> 2, sub = tid & 3;       // 64 pairs x 4 sub-chunks
    int b = pair >> 3, e = pair & 7;
    float acc = 0.f;
    const float* sp = seq + b * C_ + sub * 256;
    const float* wp = rw + e * C_ + sub * 256;
    for (int c = 0; c < 256; ++c) acc += sp[c] * wp[c];
    red[pair][sub] = acc;
  }
  __syncthreads();
  if (tid < B_ * E_)
    pr[tid >> 3][tid & 7] = red[tid][0] + red[tid][1] + red[tid][2] + red[tid][3];
  __syncthreads();
  if (tid < B_) {
    int b = tid;
    float mx = pr[b][0];
#pragma unroll
    for (int e = 1; e < E_; ++e) mx = fmaxf(mx, pr[b][e]);
    float p[E_]; float sum = 0.f;
#pragma unroll
    for (int e = 0; e < E_; ++e) { p[e] = __expf(pr[b][e] - mx); sum += p[e]; }
    float inv = 1.0f / sum;
#pragma unroll
    for (int e = 0; e < E_; ++e) { p[e] *= inv; pr[b][e] = p[e]; }
    int i0 = 0;
#pragma unroll
    for (int e = 1; e < E_; ++e) if (p[e] > p[i0]) i0 = e;
    int i1 = (i0 == 0) ? 1 : 0;
#pragma unroll
    for (int e = 0; e < E_; ++e) if (e != i0 && p[e] > p[i1]) i1 = e;
    float s2 = p[i0] + p[i1];
    sel[b * 2 + 0] = i0; sel[b * 2 + 1] = i1;
    wv[b * 2 + 0] = p[i0] / s2; wv[b * 2 + 1] = p[i1] / s2;
    ss[b][0] = i0; ss[b][1] = i1;
  }
  __syncthreads();
  if (tid == 0) {
    float loss = 0.f;
    for (int e = 0; e < E_; ++e) {
      float imp = 0.f, ld = 0.f;
      for (int b = 0; b < B_; ++b) {
        imp += pr[b][e];
        ld += ((ss[b][0] == e) || (ss[b][1] == e)) ? 1.f : 0.f;
      }
      loss += (imp / (float)B_) * (ld / (float)B_);
    }
    loss_out[0] = loss * (float)E_;
  }
}

// ---------------- transpose+cast: [R][Cc] f32 -> [Cc][R] bf16, 64x64 tiles ----------------
__global__ void k_transpose(const float* __restrict__ src, unsigned short* __restrict__ dst,
                            int R, int Cc) {
  __shared__ float tile[64][65];
  const size_t sl = (size_t)blockIdx.z * R * Cc;
  int c0 = blockIdx.x * 64, r0 = blockIdx.y * 64;
  int tx = threadIdx.x & 15, ty = threadIdx.x >> 4;  // ty 0..15
#pragma unroll
  for (int p = 0; p < 4; ++p) {
    int r = p * 16 + ty;
    v4f v = *(const v4f*)(src + sl + (size_t)(r0 + r) * Cc + c0 + tx * 4);
    tile[r][tx * 4 + 0] = v.x; tile[r][tx * 4 + 1] = v.y;
    tile[r][tx * 4 + 2] = v.z; tile[r][tx * 4 + 3] = v.w;
  }
  __syncthreads();
#pragma unroll
  for (int p = 0; p < 4; ++p) {
    int c = p * 16 + ty;      // output row
    int rr = tx * 4;
    ushort4 o;
    o.x = f2bf(tile[rr + 0][c]); o.y = f2bf(tile[rr + 1][c]);
    o.z = f2bf(tile[rr + 2][c]); o.w = f2bf(tile[rr + 3][c]);
    *(ushort4*)(dst + sl + (size_t)(c0 + c) * R + r0 + rr) = o;
  }
}

// ---------------- GEMM core: 128x128 tile, BK=32, bf16 MFMA ----------------
// LDS tiles stored CHUNK-TRANSPOSED: 16B chunk p = q_k*128 + row (q_k = k/8, row 0..127).
// Fragment ds_read_b128 then has 8 consecutive lanes covering all 32 banks exactly
// once -> conflict-free (vs 8-way conflict of row-major [128][32]).

__device__ __forceinline__ void gemm_seg(const unsigned short* A, int lda,
                                         const unsigned short* Bt, int ldb,
                                         int Kd, int row0, int col0,
                                         unsigned short* As, unsigned short* Bs,
                                         v4f (&acc)[4][4]) {
  const int tid = threadIdx.x;
  const int lane = tid & 63;
  const int wave = __builtin_amdgcn_readfirstlane(tid >> 6);
  const int r = lane & 15, q = lane >> 4;
  const int wm = wave & 1, wn = wave >> 1;
  const bool doA = (wave < 2);
  const int w = wave & 1;            // which half of the chunk space this wave stages
  const int gld = doA ? lda : ldb;
  // call j covers LDS chunks w*256 + j*64 + lane  ->  (q_k = 2w + (j>>1), row = (j&1)*64 + lane)
  const unsigned short* gp0 =
      (doA ? (A + (size_t)row0 * lda) : (Bt + (size_t)col0 * ldb)) +
      (size_t)lane * gld + w * 16;   // row=lane, k-elem offset (2w)*8
  const unsigned short* gp1 = gp0 + (size_t)64 * gld;
  unsigned short* lb = (doA ? As : Bs) + w * 2048;  // w*256 chunks * 8 ushort

  for (int kc = 0; kc < Kd; kc += 32) {
    async_load16(gp0 + kc,     lb + 0 * 512);
    async_load16(gp1 + kc,     lb + 1 * 512);
    async_load16(gp0 + kc + 8, lb + 2 * 512);
    async_load16(gp1 + kc + 8, lb + 3 * 512);
    __syncthreads();
    v8s af[4], bf[4];
#pragma unroll
    for (int i = 0; i < 4; ++i)
      af[i] = *(const v8s*)&As[(q * 128 + wm * 64 + i * 16 + r) * 8];
#pragma unroll
    for (int j = 0; j < 4; ++j)
      bf[j] = *(const v8s*)&Bs[(q * 128 + wn * 64 + j * 16 + r) * 8];
#pragma unroll
    for (int i = 0; i < 4; ++i)
#pragma unroll
      for (int j = 0; j < 4; ++j)
        acc[i][j] = __builtin_amdgcn_mfma_f32_16x16x32_bf16(af[i], bf[j], acc[i][j], 0, 0, 0);
    __syncthreads();
  }
}

// GEMM1: h[bk] = w[bk] * gelu(x[b] @ w_fc[sel[bk]])   -> bf16 [T][H]
__global__ __launch_bounds__(256, 4) void k_gemm1(
    const unsigned short* __restrict__ Xb, const unsigned short* __restrict__ Wfct,
    const int* __restrict__ sel, const float* __restrict__ wv,
    unsigned short* __restrict__ Hout) {
  __shared__ unsigned short SH[128 * 64];  // As(8KB) | Bs(8KB); reused by epilogue
  unsigned short* As = SH;
  unsigned short* Bs = SH + 128 * 32;
  const int bk = blockIdx.z;
  const int e = sel[bk];
  const float wgt = wv[bk];
  const int row0 = blockIdx.y * 128, col0 = blockIdx.x * 128;
  v4f acc[4][4];
#pragma unroll
  for (int i = 0; i < 4; ++i)
#pragma unroll
    for (int j = 0; j < 4; ++j) acc[i][j] = (v4f){0.f, 0.f, 0.f, 0.f};

  gemm_seg(Xb + (size_t)(bk >> 1) * T_ * C_, C_, Wfct + (size_t)e * H_ * C_, C_,
           C_, row0, col0, As, Bs, acc);

  const int tid = threadIdx.x;
  const int lane = tid & 63;
  const int wave = tid >> 6;
  const int r = lane & 15, q = lane >> 4;
  const int wm = wave & 1, wn = wave >> 1;
  unsigned short* Co = Hout + (size_t)bk * T_ * H_;
  // epilogue: gelu*wgt -> bf16 via LDS (half-tile passes), then b128 stores
#pragma unroll
  for (int hh = 0; hh < 2; ++hh) {
    if (wm == hh) {
#pragma unroll
      for (int i = 0; i < 4; ++i)
#pragma unroll
        for (int j = 0; j < 4; ++j)
#pragma unroll
          for (int p = 0; p < 4; ++p) {
            int lr = i * 16 + q * 4 + p;
            int lc = wn * 64 + j * 16 + r;
            float u = acc[i][j][p];
            float y = 0.7978845608028654f * (u + 0.044715f * u * u * u);
            float t = 1.0f - 2.0f / (__expf(2.0f * y) + 1.0f);
            SH[lr * 128 + lc] = f2bf(0.5f * u * (1.0f + t) * wgt);
          }
    }
    __syncthreads();
#pragma unroll
    for (int it = 0; it < 4; ++it) {
      int idx = it * 256 + tid;            // 0..1023
      int row = idx >> 4, ch = idx & 15;   // 64 rows x 16 chunks of 8 bf16
      *(v8s*)&Co[(size_t)(row0 + hh * 64 + row) * H_ + col0 + ch * 8] =
          *(const v8s*)&SH[row * 128 + ch * 8];
    }
    __syncthreads();
  }
}

// GEMM2 (split over the two selected experts): one (b,k) per z.
// k==0 partial -> P0 (d_out), k==1 partial -> P1 (ws alias).
__global__ __launch_bounds__(256, 4) void k_gemm2(
    const unsigned short* __restrict__ Hin, const unsigned short* __restrict__ Wpt,
    const int* __restrict__ sel, float* __restrict__ P0, float* __restrict__ P1) {
  __shared__ unsigned short SH[128 * 64];
  unsigned short* As = SH;
  unsigned short* Bs = SH + 128 * 32;
  const int bk = blockIdx.z;
  const int b = bk >> 1, k = bk & 1;
  const int e = sel[bk];
  const int row0 = blockIdx.y * 128, col0 = blockIdx.x * 128;
  v4f acc[4][4];
#pragma unroll
  for (int i = 0; i < 4; ++i)
#pragma unroll
    for (int j = 0; j < 4; ++j) acc[i][j] = (v4f){0.f, 0.f, 0.f, 0.f};

  gemm_seg(Hin + (size_t)bk * T_ * H_, H_, Wpt + (size_t)e * C_ * H_, H_,
           H_, row0, col0, As, Bs, acc);

  const int lane = threadIdx.x & 63;
  const int wave = threadIdx.x >> 6;
  const int r = lane & 15, q = lane >> 4;
  const int wm = wave & 1, wn = wave >> 1;
  float* Co = (k == 0 ? P0 : P1) + (size_t)b * T_ * C_;
#pragma unroll
  for (int i = 0; i < 4; ++i) {
    int gr = row0 + wm * 64 + i * 16 + q * 4;
#pragma unroll
    for (int j = 0; j < 4; ++j) {
      int gc = col0 + wn * 64 + j * 16 + r;
#pragma unroll
      for (int p = 0; p < 4; ++p)
        Co[(size_t)(gr + p) * C_ + gc] = acc[i][j][p];
    }
  }
}

// out += P1
__global__ void k_add(float* __restrict__ out, const float* __restrict__ p1) {
  size_t i = ((size_t)blockIdx.x * 256 + threadIdx.x) * 4;
  v4f a = *(const v4f*)(out + i);
  v4f b = *(const v4f*)(p1 + i);
  a += b;
  *(v4f*)(out + i) = a;
}

// ---------------- launch ----------------

extern "C" void kernel_launch(void* const* d_in, const int* in_sizes, int n_in,
                              void* d_out, int out_size, void* d_ws, size_t ws_size,
                              hipStream_t stream) {
  const float* x   = (const float*)d_in[0];
  const float* rw  = (const float*)d_in[1];
  const float* wfc = (const float*)d_in[2];
  const float* wpj = (const float*)d_in[3];
  float* out = (float*)d_out;
  char* ws = (char*)d_ws;

  // workspace layout (bytes)
  float*          part = (float*)(ws + 0);                        // 32*8*1024*4 = 1 MB
  int*            sel  = (int*)(ws + 1048576);                    // 64 B
  float*          wv   = (float*)(ws + 1048576 + 64);             // 64 B
  unsigned short* xb   = (unsigned short*)(ws + 2097152);         // 16 MB  bf16 x
  unsigned short* wfct = (unsigned short*)(ws + 2097152 + 16777216);            // 64 MB
  unsigned short* wpjt = (unsigned short*)(ws + 2097152 + 16777216 + 67108864); // 64 MB
  unsigned short* h    = (unsigned short*)(ws + 2097152 + 16777216 + 2*67108864ll); // 128 MB
  // P1 aliases xb+wfct (both dead once gemm1 completes): 33.5 MB < 80 MB available
  float*          p1   = (float*)(ws + 2097152);

  k_meanpart<<<dim3(B_ * 32), dim3(256), 0, stream>>>(x, part, xb);
  k_router<<<dim3(1), dim3(256), 0, stream>>>(part, rw, sel, wv,
                                              out + (size_t)B_ * T_ * C_);
  // w_fc [E][C][H] -> [E][H][C] bf16
  k_transpose<<<dim3(H_ / 64, C_ / 64, E_), dim3(256), 0, stream>>>(wfc, wfct, C_, H_);
  // w_proj [E][H][C] -> [E][C][H] bf16
  k_transpose<<<dim3(C_ / 64, H_ / 64, E_), dim3(256), 0, stream>>>(wpj, wpjt, H_, C_);

  k_gemm1<<<dim3(H_ / 128, T_ / 128, B_ * 2), dim3(256), 0, stream>>>(xb, wfct, sel, wv, h);
  k_gemm2<<<dim3(C_ / 128, T_ / 128, B_ * 2), dim3(256), 0, stream>>>(h, wpjt, sel, out, p1);
  k_add<<<dim3(B_ * T_ * C_ / 4 / 256), dim3(256), 0, stream>>>(out, p1);
}

// Round 4
// 771.662 us; speedup vs baseline: 1.2829x; 1.2829x over previous
//
#include <hip/hip_runtime.h>

#define B_ 8
#define T_ 1024
#define C_ 1024
#define E_ 8
#define H_ 4096

typedef float v4f __attribute__((ext_vector_type(4)));
typedef short v8s __attribute__((ext_vector_type(8)));

__device__ __forceinline__ unsigned short f2bf(float f) {
  union { float f; unsigned int u; } x; x.f = f;
  unsigned int r = x.u + 0x7fffu + ((x.u >> 16) & 1u);
  return (unsigned short)(r >> 16);
}

__device__ __forceinline__ void async_load16(const unsigned short* g, unsigned short* l) {
  __builtin_amdgcn_global_load_lds(
      (const __attribute__((address_space(1))) void*)g,
      (__attribute__((address_space(3))) void*)l, 16, 0, 0);
}

// ---------------- router phase ----------------

// stage 1: partial sums over T in 32 chunks of 32; also emits bf16 cast of x.
__global__ void k_meanpart(const float* __restrict__ x, float* __restrict__ part,
                           unsigned short* __restrict__ xb) {
  int b = blockIdx.x >> 5, tc = blockIdx.x & 31;
  int c4 = threadIdx.x * 4;
  const size_t base = (size_t)b * T_ * C_ + (size_t)tc * 32 * C_ + c4;
  const float* xp = x + base;
  v4f s = {0.f, 0.f, 0.f, 0.f};
  for (int t = 0; t < 32; ++t) {
    v4f v = *(const v4f*)(xp + (size_t)t * C_);
    s += v;
    ushort4 o;
    o.x = f2bf(v.x); o.y = f2bf(v.y); o.z = f2bf(v.z); o.w = f2bf(v.w);
    *(ushort4*)(xb + base + (size_t)t * C_) = o;
  }
  *(v4f*)(part + (size_t)(tc * B_ + b) * C_ + c4) = s;
}

// stage 2: single block: seq_rep, logits, softmax, top-2, weights, loss
__global__ void k_router(const float* __restrict__ part, const float* __restrict__ rw,
                         int* __restrict__ sel, float* __restrict__ wv,
                         float* __restrict__ loss_out) {
  __shared__ float seq[B_ * C_];
  __shared__ float red[B_ * E_][4];
  __shared__ float pr[B_][E_];
  __shared__ int ss[B_][2];
  const int tid = threadIdx.x;
  for (int idx = tid; idx < B_ * C_; idx += 256) {
    float s = 0.f;
#pragma unroll
    for (int tc = 0; tc < 32; ++tc) s += part[(size_t)tc * B_ * C_ + idx];
    seq[idx] = s * (1.0f / T_);
  }
  __syncthreads();
  {
    int pair = tid >> 2, sub = tid & 3;
    int b = pair >> 3, e = pair & 7;
    float acc = 0.f;
    const float* sp = seq + b * C_ + sub * 256;
    const float* wp = rw + e * C_ + sub * 256;
    for (int c = 0; c < 256; ++c) acc += sp[c] * wp[c];
    red[pair][sub] = acc;
  }
  __syncthreads();
  if (tid < B_ * E_)
    pr[tid >> 3][tid & 7] = red[tid][0] + red[tid][1] + red[tid][2] + red[tid][3];
  __syncthreads();
  if (tid < B_) {
    int b = tid;
    float mx = pr[b][0];
#pragma unroll
    for (int e = 1; e < E_; ++e) mx = fmaxf(mx, pr[b][e]);
    float p[E_]; float sum = 0.f;
#pragma unroll
    for (int e = 0; e < E_; ++e) { p[e] = __expf(pr[b][e] - mx); sum += p[e]; }
    float inv = 1.0f / sum;
#pragma unroll
    for (int e = 0; e < E_; ++e) { p[e] *= inv; pr[b][e] = p[e]; }
    int i0 = 0;
#pragma unroll
    for (int e = 1; e < E_; ++e) if (p[e] > p[i0]) i0 = e;
    int i1 = (i0 == 0) ? 1 : 0;
#pragma unroll
    for (int e = 0; e < E_; ++e) if (e != i0 && p[e] > p[i1]) i1 = e;
    float s2 = p[i0] + p[i1];
    sel[b * 2 + 0] = i0; sel[b * 2 + 1] = i1;
    wv[b * 2 + 0] = p[i0] / s2; wv[b * 2 + 1] = p[i1] / s2;
    ss[b][0] = i0; ss[b][1] = i1;
  }
  __syncthreads();
  if (tid == 0) {
    float loss = 0.f;
    for (int e = 0; e < E_; ++e) {
      float imp = 0.f, ld = 0.f;
      for (int b = 0; b < B_; ++b) {
        imp += pr[b][e];
        ld += ((ss[b][0] == e) || (ss[b][1] == e)) ? 1.f : 0.f;
      }
      loss += (imp / (float)B_) * (ld / (float)B_);
    }
    loss_out[0] = loss * (float)E_;
  }
}

// ---------------- transpose+cast: [R][Cc] f32 -> [Cc][R] bf16, 64x64 tiles ----------------
__global__ void k_transpose(const float* __restrict__ src, unsigned short* __restrict__ dst,
                            int R, int Cc) {
  __shared__ float tile[64][65];
  const size_t sl = (size_t)blockIdx.z * R * Cc;
  int c0 = blockIdx.x * 64, r0 = blockIdx.y * 64;
  int tx = threadIdx.x & 15, ty = threadIdx.x >> 4;
#pragma unroll
  for (int p = 0; p < 4; ++p) {
    int r = p * 16 + ty;
    v4f v = *(const v4f*)(src + sl + (size_t)(r0 + r) * Cc + c0 + tx * 4);
    tile[r][tx * 4 + 0] = v.x; tile[r][tx * 4 + 1] = v.y;
    tile[r][tx * 4 + 2] = v.z; tile[r][tx * 4 + 3] = v.w;
  }
  __syncthreads();
#pragma unroll
  for (int p = 0; p < 4; ++p) {
    int c = p * 16 + ty;
    int rr = tx * 4;
    ushort4 o;
    o.x = f2bf(tile[rr + 0][c]); o.y = f2bf(tile[rr + 1][c]);
    o.z = f2bf(tile[rr + 2][c]); o.w = f2bf(tile[rr + 3][c]);
    *(ushort4*)(dst + sl + (size_t)(c0 + c) * R + r0 + rr) = o;
  }
}

// ---------------- GEMM core: 128x128 tile, BK=32, bf16 MFMA ----------------
// Staging: round-2 coalesced pattern (4 lanes cover one row's 64B) but with the
// k-chunk XOR-SWIZZLED per lane: LDS pos p of row r holds k-chunk p ^ ((r>>1)&3).
// Fragment ds_read_b128 at chunk row*4 + (q ^ ((r>>1)&3)) -> start bank
// 16*(r&1) + 4*(q^s): all 32 banks covered exactly 2x per 16-row group = free
// (m136). Global coalescing preserved (same 64B segment per 4-lane group).

__device__ __forceinline__ void gemm_seg(const unsigned short* A, int lda,
                                         const unsigned short* Bt, int ldb,
                                         int Kd, int row0, int col0,
                                         unsigned short* As, unsigned short* Bs,
                                         v4f (&acc)[4][4]) {
  const int tid = threadIdx.x;
  const int lane = tid & 63;
  const int wave = __builtin_amdgcn_readfirstlane(tid >> 6);
  const int r = lane & 15, q = lane >> 4;
  const int wm = wave & 1, wn = wave >> 1;
  const int qs = q ^ ((r >> 1) & 3);           // swizzled chunk for fragment reads
  const int lrow = lane >> 2;                  // 0..15: row within 16-row call group
  const int lch = (lane & 3) ^ ((lane >> 3) & 3);  // swizzled k-chunk to fetch
  const bool doA = (wave < 2);
  const int jb = (wave & 1) * 4;
  const int gld = doA ? lda : ldb;
  const unsigned short* gbase =
      (doA ? (A + (size_t)row0 * lda) : (Bt + (size_t)col0 * ldb)) +
      (size_t)(jb * 16 + lrow) * gld + lch * 8;
  unsigned short* lbase = (doA ? As : Bs) + jb * 512;

  for (int kc = 0; kc < Kd; kc += 32) {
    const unsigned short* g = gbase + kc;
    async_load16(g + 0 * 16 * (size_t)gld, lbase + 0 * 512);
    async_load16(g + 1 * 16 * (size_t)gld, lbase + 1 * 512);
    async_load16(g + 2 * 16 * (size_t)gld, lbase + 2 * 512);
    async_load16(g + 3 * 16 * (size_t)gld, lbase + 3 * 512);
    __syncthreads();
    v8s af[4], bf[4];
#pragma unroll
    for (int i = 0; i < 4; ++i)
      af[i] = *(const v8s*)&As[((wm * 64 + i * 16 + r) * 4 + qs) * 8];
#pragma unroll
    for (int j = 0; j < 4; ++j)
      bf[j] = *(const v8s*)&Bs[((wn * 64 + j * 16 + r) * 4 + qs) * 8];
#pragma unroll
    for (int i = 0; i < 4; ++i)
#pragma unroll
      for (int j = 0; j < 4; ++j)
        acc[i][j] = __builtin_amdgcn_mfma_f32_16x16x32_bf16(af[i], bf[j], acc[i][j], 0, 0, 0);
    __syncthreads();
  }
}

// GEMM1: h[bk] = w[bk] * gelu(x[b] @ w_fc[sel[bk]])   -> bf16 [T][H]
__global__ __launch_bounds__(256, 4) void k_gemm1(
    const unsigned short* __restrict__ Xb, const unsigned short* __restrict__ Wfct,
    const int* __restrict__ sel, const float* __restrict__ wv,
    unsigned short* __restrict__ Hout) {
  __shared__ unsigned short SH[128 * 64];  // As(8KB) | Bs(8KB); reused by epilogue
  unsigned short* As = SH;
  unsigned short* Bs = SH + 128 * 32;
  const int bk = blockIdx.z;
  const int e = sel[bk];
  const float wgt = wv[bk];
  const int row0 = blockIdx.y * 128, col0 = blockIdx.x * 128;
  v4f acc[4][4];
#pragma unroll
  for (int i = 0; i < 4; ++i)
#pragma unroll
    for (int j = 0; j < 4; ++j) acc[i][j] = (v4f){0.f, 0.f, 0.f, 0.f};

  gemm_seg(Xb + (size_t)(bk >> 1) * T_ * C_, C_, Wfct + (size_t)e * H_ * C_, C_,
           C_, row0, col0, As, Bs, acc);

  const int tid = threadIdx.x;
  const int lane = tid & 63;
  const int wave = tid >> 6;
  const int r = lane & 15, q = lane >> 4;
  const int wm = wave & 1, wn = wave >> 1;
  unsigned short* Co = Hout + (size_t)bk * T_ * H_;
#pragma unroll
  for (int hh = 0; hh < 2; ++hh) {
    if (wm == hh) {
#pragma unroll
      for (int i = 0; i < 4; ++i)
#pragma unroll
        for (int j = 0; j < 4; ++j)
#pragma unroll
          for (int p = 0; p < 4; ++p) {
            int lr = i * 16 + q * 4 + p;
            int lc = wn * 64 + j * 16 + r;
            float u = acc[i][j][p];
            float y = 0.7978845608028654f * (u + 0.044715f * u * u * u);
            float t = 1.0f - 2.0f / (__expf(2.0f * y) + 1.0f);
            SH[lr * 128 + lc] = f2bf(0.5f * u * (1.0f + t) * wgt);
          }
    }
    __syncthreads();
#pragma unroll
    for (int it = 0; it < 4; ++it) {
      int idx = it * 256 + tid;
      int row = idx >> 4, ch = idx & 15;
      *(v8s*)&Co[(size_t)(row0 + hh * 64 + row) * H_ + col0 + ch * 8] =
          *(const v8s*)&SH[row * 128 + ch * 8];
    }
    __syncthreads();
  }
}

// GEMM2 (split over the two selected experts): one (b,k) per z.
__global__ __launch_bounds__(256, 4) void k_gemm2(
    const unsigned short* __restrict__ Hin, const unsigned short* __restrict__ Wpt,
    const int* __restrict__ sel, float* __restrict__ P0, float* __restrict__ P1) {
  __shared__ unsigned short SH[128 * 64];
  unsigned short* As = SH;
  unsigned short* Bs = SH + 128 * 32;
  const int bk = blockIdx.z;
  const int b = bk >> 1, k = bk & 1;
  const int e = sel[bk];
  const int row0 = blockIdx.y * 128, col0 = blockIdx.x * 128;
  v4f acc[4][4];
#pragma unroll
  for (int i = 0; i < 4; ++i)
#pragma unroll
    for (int j = 0; j < 4; ++j) acc[i][j] = (v4f){0.f, 0.f, 0.f, 0.f};

  gemm_seg(Hin + (size_t)bk * T_ * H_, H_, Wpt + (size_t)e * C_ * H_, H_,
           H_, row0, col0, As, Bs, acc);

  const int lane = threadIdx.x & 63;
  const int wave = threadIdx.x >> 6;
  const int r = lane & 15, q = lane >> 4;
  const int wm = wave & 1, wn = wave >> 1;
  float* Co = (k == 0 ? P0 : P1) + (size_t)b * T_ * C_;
#pragma unroll
  for (int i = 0; i < 4; ++i) {
    int gr = row0 + wm * 64 + i * 16 + q * 4;
#pragma unroll
    for (int j = 0; j < 4; ++j) {
      int gc = col0 + wn * 64 + j * 16 + r;
#pragma unroll
      for (int p = 0; p < 4; ++p)
        Co[(size_t)(gr + p) * C_ + gc] = acc[i][j][p];
    }
  }
}

// out += P1
__global__ void k_add(float* __restrict__ out, const float* __restrict__ p1) {
  size_t i = ((size_t)blockIdx.x * 256 + threadIdx.x) * 4;
  v4f a = *(const v4f*)(out + i);
  v4f b = *(const v4f*)(p1 + i);
  a += b;
  *(v4f*)(out + i) = a;
}

// ---------------- launch ----------------

extern "C" void kernel_launch(void* const* d_in, const int* in_sizes, int n_in,
                              void* d_out, int out_size, void* d_ws, size_t ws_size,
                              hipStream_t stream) {
  const float* x   = (const float*)d_in[0];
  const float* rw  = (const float*)d_in[1];
  const float* wfc = (const float*)d_in[2];
  const float* wpj = (const float*)d_in[3];
  float* out = (float*)d_out;
  char* ws = (char*)d_ws;

  float*          part = (float*)(ws + 0);                        // 1 MB
  int*            sel  = (int*)(ws + 1048576);
  float*          wv   = (float*)(ws + 1048576 + 64);
  unsigned short* xb   = (unsigned short*)(ws + 2097152);         // 16 MB
  unsigned short* wfct = (unsigned short*)(ws + 2097152 + 16777216);            // 64 MB
  unsigned short* wpjt = (unsigned short*)(ws + 2097152 + 16777216 + 67108864); // 64 MB
  unsigned short* h    = (unsigned short*)(ws + 2097152 + 16777216 + 2*67108864ll); // 128 MB
  float*          p1   = (float*)(ws + 2097152);  // aliases dead xb+wfct after gemm1

  k_meanpart<<<dim3(B_ * 32), dim3(256), 0, stream>>>(x, part, xb);
  k_router<<<dim3(1), dim3(256), 0, stream>>>(part, rw, sel, wv,
                                              out + (size_t)B_ * T_ * C_);
  k_transpose<<<dim3(H_ / 64, C_ / 64, E_), dim3(256), 0, stream>>>(wfc, wfct, C_, H_);
  k_transpose<<<dim3(C_ / 64, H_ / 64, E_), dim3(256), 0, stream>>>(wpj, wpjt, H_, C_);

  k_gemm1<<<dim3(H_ / 128, T_ / 128, B_ * 2), dim3(256), 0, stream>>>(xb, wfct, sel, wv, h);
  k_gemm2<<<dim3(C_ / 128, T_ / 128, B_ * 2), dim3(256), 0, stream>>>(h, wpjt, sel, out, p1);
  k_add<<<dim3(B_ * T_ * C_ / 4 / 256), dim3(256), 0, stream>>>(out, p1);
}